// Round 1
// baseline (12278.165 us; speedup 1.0000x reference)
//
#include <hip/hip_runtime.h>
#include <hip/hip_bf16.h>

// Problem constants
#define B_   128
#define T_   512
#define DIN  256
#define DH   1024
#define DOUT 1024

typedef short bf16x8 __attribute__((ext_vector_type(8)));
typedef float f32x4  __attribute__((ext_vector_type(4)));
typedef unsigned short u16;

// Manual RNE f32->bf16 (avoids header API variance; inputs finite)
static __device__ __forceinline__ u16 f2bf(float f) {
    unsigned u = __float_as_uint(f);
    u += 0x7FFFu + ((u >> 16) & 1u);
    return (u16)(u >> 16);
}
static __device__ __forceinline__ float bf2f(u16 h) {
    return __uint_as_float(((unsigned)h) << 16);
}

// ---------------- elementwise helpers ----------------

__global__ void f32_to_bf16_k(const float* __restrict__ in, u16* __restrict__ out, int n) {
    int i = blockIdx.x * 256 + threadIdx.x;
    int stride = gridDim.x * 256;
    for (; i < n; i += stride) out[i] = f2bf(in[i]);
}

__global__ void zero_u16_k(u16* __restrict__ p, int n) {
    int i = blockIdx.x * 256 + threadIdx.x;
    if (i < n) p[i] = 0;
}

// out[b, 0, :] = 0
__global__ void zero_row0_k(float* __restrict__ out) {
    int i = blockIdx.x * 256 + threadIdx.x;   // 128*1024 threads
    int b = i >> 10, c = i & 1023;
    out[(size_t)b * ((T_ + 1) * DOUT) + c] = 0.f;
}

// ---------------- phase 1: X = seq @ Wx^T + Wx_b + Wh_b, stored (T,B,DH) bf16 ----------------
// wave tile 16(m) x 64(n); 65536 waves, 4 waves/block

__global__ void proj_x_k(const u16* __restrict__ seqb, const u16* __restrict__ Wx,
                         const float* __restrict__ Wx_b, const float* __restrict__ Wh_b,
                         u16* __restrict__ XS) {
    int wave = threadIdx.x >> 6;
    int lane = threadIdx.x & 63;
    int g = blockIdx.x * 4 + wave;           // 0..65535
    int mt = g >> 4, nt = g & 15;
    int m0 = mt << 4, n0 = nt << 6;
    int lr = lane & 15, lq = lane >> 4;

    // A row: output row r = t*B + b  ->  seq row (b*T + t)
    int r = m0 + lr;
    int b = r & (B_ - 1), t = r >> 7;
    const bf16x8* Arow = (const bf16x8*)(seqb + (size_t)(b * T_ + t) * DIN);

    f32x4 acc[4] = {};
    for (int k0 = 0; k0 < DIN; k0 += 32) {
        bf16x8 a = Arow[(k0 >> 3) + lq];
#pragma unroll
        for (int f = 0; f < 4; ++f) {
            const bf16x8* Brow = (const bf16x8*)(Wx + (size_t)(n0 + f * 16 + lr) * DIN);
            acc[f] = __builtin_amdgcn_mfma_f32_16x16x32_bf16(a, Brow[(k0 >> 3) + lq], acc[f], 0, 0, 0);
        }
    }
#pragma unroll
    for (int f = 0; f < 4; ++f)
#pragma unroll
        for (int j = 0; j < 4; ++j) {
            int row = m0 + lq * 4 + j;
            int col = n0 + f * 16 + lr;
            float v = acc[f][j] + Wx_b[col] + Wh_b[col];
            XS[(size_t)row * DH + col] = f2bf(v);
        }
}

// ---------------- phase 2: one timestep ----------------
// s = h_in @ Wh^T + X_t  (X_t already holds Wx_b + Wh_b)
// Xt slot overwritten with bf16(s); h_out = bf16(tanh(s))
// grid: 128 blocks x 64 threads (one wave each), tile 16x64

__global__ void rnn_step_k(const u16* __restrict__ h_in, u16* __restrict__ h_out,
                           u16* __restrict__ Xt, const u16* __restrict__ Wh) {
    int lane = threadIdx.x & 63;
    int g = blockIdx.x;                      // 0..127
    int mt = g >> 4, nt = g & 15;
    int m0 = mt << 4, n0 = nt << 6;
    int lr = lane & 15, lq = lane >> 4;

    const bf16x8* Arow = (const bf16x8*)(h_in + (size_t)(m0 + lr) * DH);

    f32x4 acc[4] = {};
    for (int k0 = 0; k0 < DH; k0 += 32) {
        bf16x8 a = Arow[(k0 >> 3) + lq];
#pragma unroll
        for (int f = 0; f < 4; ++f) {
            const bf16x8* Brow = (const bf16x8*)(Wh + (size_t)(n0 + f * 16 + lr) * DH);
            acc[f] = __builtin_amdgcn_mfma_f32_16x16x32_bf16(a, Brow[(k0 >> 3) + lq], acc[f], 0, 0, 0);
        }
    }
#pragma unroll
    for (int f = 0; f < 4; ++f)
#pragma unroll
        for (int j = 0; j < 4; ++j) {
            int row = m0 + lq * 4 + j;
            int col = n0 + f * 16 + lr;
            size_t idx = (size_t)row * DH + col;
            float s = acc[f][j] + bf2f(Xt[idx]);
            Xt[idx] = f2bf(s);
            h_out[idx] = f2bf(tanhf(s));
        }
}

// ---------------- phase 3: O = S @ Wo^T + Wo_b -> d_out[b, t+1, :] ----------------

__global__ void wo_k(const u16* __restrict__ S, const u16* __restrict__ Wo,
                     const float* __restrict__ Wo_b, float* __restrict__ out) {
    int wave = threadIdx.x >> 6;
    int lane = threadIdx.x & 63;
    int g = blockIdx.x * 4 + wave;           // 0..65535
    int mt = g >> 4, nt = g & 15;
    int m0 = mt << 4, n0 = nt << 6;
    int lr = lane & 15, lq = lane >> 4;

    const bf16x8* Arow = (const bf16x8*)(S + (size_t)(m0 + lr) * DH);

    f32x4 acc[4] = {};
    for (int k0 = 0; k0 < DH; k0 += 32) {
        bf16x8 a = Arow[(k0 >> 3) + lq];
#pragma unroll
        for (int f = 0; f < 4; ++f) {
            const bf16x8* Brow = (const bf16x8*)(Wo + (size_t)(n0 + f * 16 + lr) * DH);
            acc[f] = __builtin_amdgcn_mfma_f32_16x16x32_bf16(a, Brow[(k0 >> 3) + lq], acc[f], 0, 0, 0);
        }
    }
#pragma unroll
    for (int f = 0; f < 4; ++f)
#pragma unroll
        for (int j = 0; j < 4; ++j) {
            int r2 = m0 + lq * 4 + j;        // S row = t*B + b
            int col = n0 + f * 16 + lr;
            int t = r2 >> 7, b = r2 & (B_ - 1);
            out[(size_t)b * ((T_ + 1) * DOUT) + (size_t)(t + 1) * DOUT + col] = acc[f][j] + Wo_b[col];
        }
}

// ---------------- launcher ----------------

extern "C" void kernel_launch(void* const* d_in, const int* in_sizes, int n_in,
                              void* d_out, int out_size, void* d_ws, size_t ws_size,
                              hipStream_t stream) {
    const float* seq  = (const float*)d_in[0];
    const float* Wh_w = (const float*)d_in[1];
    const float* Wh_b = (const float*)d_in[2];
    const float* Wx_w = (const float*)d_in[3];
    const float* Wx_b = (const float*)d_in[4];
    const float* Wo_w = (const float*)d_in[5];
    const float* Wo_b = (const float*)d_in[6];
    float* out = (float*)d_out;

    // workspace carve-up
    size_t off = 0;
    auto carve = [&](size_t bytes) {
        void* p = (char*)d_ws + off;
        off += (bytes + 255) & ~(size_t)255;
        return p;
    };
    u16* seqb = (u16*)carve((size_t)B_ * T_ * DIN * 2);
    u16* Whb  = (u16*)carve((size_t)DH * DH * 2);
    u16* Wxb  = (u16*)carve((size_t)DH * DIN * 2);
    u16* Wob  = (u16*)carve((size_t)DH * DH * 2);
    u16* XS   = (u16*)carve((size_t)T_ * B_ * DH * 2);   // X, overwritten by S in place
    u16* h0   = (u16*)carve((size_t)B_ * DH * 2);
    u16* h1   = (u16*)carve((size_t)B_ * DH * 2);

    // phase 0: casts
    f32_to_bf16_k<<<2048, 256, 0, stream>>>(seq,  seqb, B_ * T_ * DIN);
    f32_to_bf16_k<<<256,  256, 0, stream>>>(Wh_w, Whb,  DH * DH);
    f32_to_bf16_k<<<64,   256, 0, stream>>>(Wx_w, Wxb,  DH * DIN);
    f32_to_bf16_k<<<256,  256, 0, stream>>>(Wo_w, Wob,  DH * DH);

    // phase 1: input projection (+ both biases folded in)
    proj_x_k<<<16384, 256, 0, stream>>>(seqb, Wxb, Wx_b, Wh_b, XS);

    // h0 = 0
    zero_u16_k<<<(B_ * DH + 255) / 256, 256, 0, stream>>>(h0, B_ * DH);

    // phase 2: sequential recurrence
    for (int t = 0; t < T_; ++t) {
        u16* hi = (t & 1) ? h1 : h0;
        u16* ho = (t & 1) ? h0 : h1;
        rnn_step_k<<<128, 64, 0, stream>>>(hi, ho, XS + (size_t)t * B_ * DH, Whb);
    }

    // phase 3: output projection
    zero_row0_k<<<(B_ * DOUT + 255) / 256, 256, 0, stream>>>(out);
    wo_k<<<16384, 256, 0, stream>>>(XS, Wob, Wo_b, out);
}

// Round 2
// 4821.746 us; speedup vs baseline: 2.5464x; 2.5464x over previous
//
#include <hip/hip_runtime.h>
#include <hip/hip_bf16.h>

// Problem constants
#define B_   128
#define T_   512
#define DIN  256
#define DH   1024
#define DOUT 1024

typedef short bf16x8 __attribute__((ext_vector_type(8)));
typedef float f32x4  __attribute__((ext_vector_type(4)));
typedef unsigned short u16;

static __device__ __forceinline__ u16 f2bf(float f) {
    unsigned u = __float_as_uint(f);
    u += 0x7FFFu + ((u >> 16) & 1u);
    return (u16)(u >> 16);
}
static __device__ __forceinline__ float bf2f(u16 h) {
    return __uint_as_float(((unsigned)h) << 16);
}

// Fragment layout per (t, group): element (r in 0..15, col in 0..1023) at
//   idx = (col>>5)*512 + ((col>>3)&3)*128 + r*8 + (col&7)   [u16 units]
// A-frag read for k-tile kt: lane l loads 16B at u16 offset kt*512 + l*8  (coalesced)

// ---------------- elementwise helpers ----------------

__global__ void f32_to_bf16_k(const float* __restrict__ in, u16* __restrict__ out, int n) {
    int i = blockIdx.x * 256 + threadIdx.x;
    int stride = gridDim.x * 256;
    for (; i < n; i += stride) out[i] = f2bf(in[i]);
}

__global__ void zero32_k(unsigned* __restrict__ p, int n) {
    int i = blockIdx.x * 256 + threadIdx.x;
    if (i < n) p[i] = 0;
}

__global__ void zero_row0_k(float* __restrict__ out) {
    int i = blockIdx.x * 256 + threadIdx.x;   // 128*1024 threads
    int b = i >> 10, c = i & 1023;
    out[(size_t)b * ((T_ + 1) * DOUT) + c] = 0.f;
}

// ---------------- phase 1: X = seq @ Wx^T + Wx_b + Wh_b -> frag layout ----------------

__global__ void proj_x_k(const u16* __restrict__ seqb, const u16* __restrict__ Wx,
                         const float* __restrict__ Wx_b, const float* __restrict__ Wh_b,
                         u16* __restrict__ Xf) {
    int wave = threadIdx.x >> 6;
    int lane = threadIdx.x & 63;
    int g = blockIdx.x * 4 + wave;           // 0..65535
    int mt = g >> 4, nt = g & 15;
    int t = mt >> 3, gb = mt & 7;
    int n0 = nt << 6;
    int lr = lane & 15, lq = lane >> 4;

    int b = gb * 16 + lr;
    const u16* Arow = seqb + (size_t)(b * T_ + t) * DIN;

    f32x4 acc[4] = {};
    for (int k0 = 0; k0 < DIN; k0 += 32) {
        bf16x8 a = *(const bf16x8*)(Arow + k0 + lq * 8);
#pragma unroll
        for (int f = 0; f < 4; ++f) {
            const u16* Brow = Wx + (size_t)(n0 + f * 16 + lr) * DIN;
            acc[f] = __builtin_amdgcn_mfma_f32_16x16x32_bf16(a, *(const bf16x8*)(Brow + k0 + lq * 8), acc[f], 0, 0, 0);
        }
    }
    u16* Xg = Xf + ((size_t)t * 8 + gb) * 16384;
#pragma unroll
    for (int f = 0; f < 4; ++f)
#pragma unroll
        for (int j = 0; j < 4; ++j) {
            int r = lq * 4 + j;
            int col = n0 + f * 16 + lr;
            float v = acc[f][j] + Wx_b[col] + Wh_b[col];
            Xg[(col >> 5) * 512 + ((col >> 3) & 3) * 128 + r * 8 + (col & 7)] = f2bf(v);
        }
}

// ---------------- phase 2: persistent recurrence ----------------
// 128 blocks x 256 threads, all co-resident. Block = (colblk 0..15, gb 0..7).
// 4 waves: colh = w&1 (32-col half), kh = w>>1 (512-K half).
// Wh slice (32 cols x 512 K) lives in registers for the whole kernel.

__global__ __launch_bounds__(256, 1) void rnn_persist_k(
    const u16* __restrict__ Wh, u16* __restrict__ Xf,
    u16* __restrict__ hbuf, int* __restrict__ cnt)
{
    const int tid  = threadIdx.x;
    const int lane = tid & 63;
    const int w    = tid >> 6;
    const int colh = w & 1, kh = w >> 1;
    const int gb     = blockIdx.x & 7;       // group -> same XCD under round-robin
    const int colblk = blockIdx.x >> 3;      // 0..15
    const int n0c = colblk * 64 + colh * 32;
    const int lr = lane & 15, lq = lane >> 4;

    // preload Wh B-frags: 32 frags x 16B/lane = 128 VGPRs
    bf16x8 Bf0[16], Bf1[16];
    {
        const u16* wr = Wh + (size_t)(n0c + lr) * DH + kh * 512;
#pragma unroll
        for (int kt = 0; kt < 16; ++kt) {
            Bf0[kt] = *(const bf16x8*)(wr + kt * 32 + lq * 8);
            Bf1[kt] = *(const bf16x8*)(wr + 16 * DH + kt * 32 + lq * 8);
        }
    }

    __shared__ f32x4 xch[2][2][64];          // [colh][frag f][lane]

    // finalize column for this lane (frag f = kh): c fixed per lane
    const int c = n0c + kh * 16 + lr;
    const int fbase = (c >> 5) * 512 + ((c >> 3) & 3) * 128 + (c & 7);

    for (int t = 0; t < T_; ++t) {
        const u16* hin = hbuf + (size_t)(t & 1) * 131072 + gb * 16384 + kh * 8192;
        bf16x8 af[16];
#pragma unroll
        for (int kt = 0; kt < 16; ++kt)
            af[kt] = *(const bf16x8*)(hin + kt * 512 + lane * 8);

        f32x4 a0 = {}, a1 = {};
#pragma unroll
        for (int kt = 0; kt < 16; ++kt) {
            a0 = __builtin_amdgcn_mfma_f32_16x16x32_bf16(af[kt], Bf0[kt], a0, 0, 0, 0);
            a1 = __builtin_amdgcn_mfma_f32_16x16x32_bf16(af[kt], Bf1[kt], a1, 0, 0, 0);
        }

        // K-split combine: wave (colh,kh) finalizes frag f=kh, shares frag f=1-kh
        xch[colh][1 ^ kh][lane] = kh ? a0 : a1;
        __syncthreads();
        f32x4 mine = kh ? a1 : a0;
        f32x4 part = xch[colh][kh][lane];
        mine = mine + part;

        u16* Xg  = Xf + ((size_t)t * 8 + gb) * 16384;
        u16* hog = hbuf + (size_t)((t + 1) & 1) * 131072 + gb * 16384;
#pragma unroll
        for (int j = 0; j < 4; ++j) {
            int idx = fbase + (lq * 4 + j) * 8;
            float s = mine[j] + bf2f(Xg[idx]);
            Xg[idx]  = f2bf(s);              // s kept for phase 3 (in place)
            hog[idx] = f2bf(tanhf(s));
        }

        if (t != T_ - 1) {
            __syncthreads();                 // drains vmcnt for all waves
            if (tid == 0) {
                int* c0 = &cnt[t * 8 + gb];
                __hip_atomic_fetch_add(c0, 1, __ATOMIC_RELEASE, __HIP_MEMORY_SCOPE_AGENT);
                while (__hip_atomic_load(c0, __ATOMIC_RELAXED, __HIP_MEMORY_SCOPE_AGENT) < 16)
                    __builtin_amdgcn_s_sleep(2);
                __hip_atomic_fetch_add(c0, 0, __ATOMIC_ACQUIRE, __HIP_MEMORY_SCOPE_AGENT);
            }
            __syncthreads();
        }
    }
}

// ---------------- phase 3: O = S @ Wo^T + Wo_b -> d_out[b, t+1, :] ----------------

__global__ void wo_k(const u16* __restrict__ XSf, const u16* __restrict__ Wo,
                     const float* __restrict__ Wo_b, float* __restrict__ out) {
    int wave = threadIdx.x >> 6;
    int lane = threadIdx.x & 63;
    int g = blockIdx.x * 4 + wave;           // 0..65535
    int mt = g >> 4, nt = g & 15;
    int n0 = nt << 6;
    int lr = lane & 15, lq = lane >> 4;

    const u16* Ab = XSf + (size_t)mt * 16384;

    f32x4 acc[4] = {};
    for (int kt = 0; kt < 32; ++kt) {
        bf16x8 a = *(const bf16x8*)(Ab + kt * 512 + lane * 8);
#pragma unroll
        for (int f = 0; f < 4; ++f) {
            const u16* Brow = Wo + (size_t)(n0 + f * 16 + lr) * DH;
            acc[f] = __builtin_amdgcn_mfma_f32_16x16x32_bf16(a, *(const bf16x8*)(Brow + kt * 32 + lq * 8), acc[f], 0, 0, 0);
        }
    }
    int t = mt >> 3, gb = mt & 7;
#pragma unroll
    for (int f = 0; f < 4; ++f)
#pragma unroll
        for (int j = 0; j < 4; ++j) {
            int b = gb * 16 + lq * 4 + j;
            int col = n0 + f * 16 + lr;
            out[(size_t)b * ((T_ + 1) * DOUT) + (size_t)(t + 1) * DOUT + col] = acc[f][j] + Wo_b[col];
        }
}

// ---------------- launcher ----------------

extern "C" void kernel_launch(void* const* d_in, const int* in_sizes, int n_in,
                              void* d_out, int out_size, void* d_ws, size_t ws_size,
                              hipStream_t stream) {
    const float* seq  = (const float*)d_in[0];
    const float* Wh_w = (const float*)d_in[1];
    const float* Wh_b = (const float*)d_in[2];
    const float* Wx_w = (const float*)d_in[3];
    const float* Wx_b = (const float*)d_in[4];
    const float* Wo_w = (const float*)d_in[5];
    const float* Wo_b = (const float*)d_in[6];
    float* out = (float*)d_out;

    size_t off = 0;
    auto carve = [&](size_t bytes) {
        void* p = (char*)d_ws + off;
        off += (bytes + 255) & ~(size_t)255;
        return p;
    };
    u16* seqb = (u16*)carve((size_t)B_ * T_ * DIN * 2);
    u16* Whb  = (u16*)carve((size_t)DH * DH * 2);
    u16* Wxb  = (u16*)carve((size_t)DH * DIN * 2);
    u16* Wob  = (u16*)carve((size_t)DH * DH * 2);
    u16* Xf   = (u16*)carve((size_t)T_ * B_ * DH * 2);   // X, overwritten by S in place (frag layout)
    u16* hbuf = (u16*)carve((size_t)2 * B_ * DH * 2);    // double-buffered h, frag layout
    int* cnt  = (int*)carve((size_t)T_ * 8 * 4);

    // phase 0: casts
    f32_to_bf16_k<<<2048, 256, 0, stream>>>(seq,  seqb, B_ * T_ * DIN);
    f32_to_bf16_k<<<256,  256, 0, stream>>>(Wh_w, Whb,  DH * DH);
    f32_to_bf16_k<<<64,   256, 0, stream>>>(Wx_w, Wxb,  DH * DIN);
    f32_to_bf16_k<<<256,  256, 0, stream>>>(Wo_w, Wob,  DH * DH);

    // phase 1: input projection (+ both biases folded in), frag layout
    proj_x_k<<<16384, 256, 0, stream>>>(seqb, Wxb, Wx_b, Wh_b, Xf);

    // zero h0 and barrier counters
    zero32_k<<<256, 256, 0, stream>>>((unsigned*)hbuf, B_ * DH / 2);
    zero32_k<<<16,  256, 0, stream>>>((unsigned*)cnt, T_ * 8);

    // phase 2: persistent recurrence (128 blocks, all co-resident)
    rnn_persist_k<<<128, 256, 0, stream>>>(Whb, Xf, hbuf, cnt);

    // phase 3: output projection
    zero_row0_k<<<(B_ * DOUT + 255) / 256, 256, 0, stream>>>(out);
    wo_k<<<16384, 256, 0, stream>>>(Xf, Wob, Wo_b, out);
}